// Round 2
// baseline (15719.229 us; speedup 1.0000x reference)
//
#include <hip/hip_runtime.h>
#include <stdint.h>

// ---------------------------------------------------------------------------
// RnnInferenceNetwork: GRU-variant scan, T=1024, SB=256 rows, H=512, L=64.
// Design: 128 persistent wgs (8 row-blocks x 16 col-groups), weights resident
// in LDS (W_h/W_xz slices) + VGPRs (W_d frags), custom device-scope grid
// barrier, h/u state exchanged via LLC. x@W_x precomputed (bf16 MFMA).
// R2 fixes: (1) phase-2 n-preact now includes z_prev@W_x[D:,2H:] (was the
// entropy bug); (2) fp32 register carry of own h tile for the combine;
// (3) raw (softplus input) and z-gate kept fp32 in LDS.
// ---------------------------------------------------------------------------

#define NWG  128u

typedef __bf16 bf16;
typedef __attribute__((ext_vector_type(8))) __bf16 bf16x8;
typedef __attribute__((ext_vector_type(8))) short  s16x8;
typedef __attribute__((ext_vector_type(4))) float  f32x4;
typedef __attribute__((ext_vector_type(4))) unsigned int u32x4;

__device__ __forceinline__ f32x4 mfma16(bf16x8 a, bf16x8 b, f32x4 c) {
  return __builtin_amdgcn_mfma_f32_16x16x32_bf16(
      __builtin_bit_cast(s16x8, a), __builtin_bit_cast(s16x8, b), c, 0, 0, 0);
}

// --------------------------- repack weights --------------------------------
// B-fragment layout: [kc][q][n][j] ; element = W[k = kc*32+q*8+j][col(n)]
// Whs: [c16][kc16][q4][n96][j8]   col = (n/32)*512 + 32c + (n%32)   (W_h)
// Wxz: [c16][kc2 ][q4][n96][j8]   same col, rows 256..319 of W_x
// Wdf: [kc16][q4][n128][j8]       col = n                            (W_d)
// Wxx: [c16][kc8 ][q4][n96][j8]   same col, rows 0..255 of W_x
__global__ void repack_kernel(const float* __restrict__ W_x,
                              const float* __restrict__ W_h,
                              const float* __restrict__ W_d,
                              bf16* __restrict__ Whs, bf16* __restrict__ Wxz,
                              bf16* __restrict__ Wdf, bf16* __restrict__ Wxx)
{
  unsigned e = blockIdx.x*256u + threadIdx.x;
  if (e < 786432u) {
    unsigned c = e/49152u, r0 = e%49152u;
    unsigned kc = r0/3072u, r1 = r0%3072u;
    unsigned q = r1/768u, r2 = r1%768u;
    unsigned n = r2/8u, j = r2%8u;
    unsigned k = kc*32u + q*8u + j;
    unsigned colg = (n>>5)*512u + c*32u + (n&31u);
    Whs[e] = (bf16)W_h[k*1536u + colg];
  } else if (e < 884736u) {
    unsigned e1 = e - 786432u;
    unsigned c = e1/6144u, r0 = e1%6144u;
    unsigned kc = r0/3072u, r1 = r0%3072u;
    unsigned q = r1/768u, r2 = r1%768u;
    unsigned n = r2/8u, j = r2%8u;
    unsigned k = 256u + kc*32u + q*8u + j;
    unsigned colg = (n>>5)*512u + c*32u + (n&31u);
    Wxz[e1] = (bf16)W_x[k*1536u + colg];
  } else if (e < 950272u) {
    unsigned e2 = e - 884736u;
    unsigned kc = e2/4096u, r0 = e2%4096u;
    unsigned q = r0/1024u, r1 = r0%1024u;
    unsigned n = r1/8u, j = r1%8u;
    unsigned k = kc*32u + q*8u + j;
    Wdf[e2] = (bf16)W_d[k*128u + n];
  } else if (e < 1343488u) {
    unsigned e3 = e - 950272u;
    unsigned c = e3/24576u, r0 = e3%24576u;
    unsigned kc = r0/3072u, r1 = r0%3072u;
    unsigned q = r1/768u, r2 = r1%768u;
    unsigned n = r2/8u, j = r2%8u;
    unsigned k = kc*32u + q*8u + j;
    unsigned colg = (n>>5)*512u + c*32u + (n&31u);
    Wxx[e3] = (bf16)W_x[k*1536u + colg];
  }
}

// ----------------- transpose x [B][T][D] f32 -> xT [t][b][d] bf16 ----------
__global__ void xpose_kernel(const float* __restrict__ x, bf16* __restrict__ xT)
{
  unsigned t = blockIdx.x, tid = threadIdx.x;
  unsigned row = tid>>2, seg = tid&3u;
  const float* src = x + ((size_t)row*1024u + t)*256u + seg*64u;
  bf16* dst = xT + (size_t)t*16384u + row*256u + seg*64u;
  #pragma unroll
  for (int i = 0; i < 8; ++i) {
    f32x4 v0 = *(const f32x4*)(src + i*8);
    f32x4 v1 = *(const f32x4*)(src + i*8 + 4);
    bf16x8 o;
    #pragma unroll
    for (int j = 0; j < 4; ++j) { o[j] = (bf16)v0[j]; o[4+j] = (bf16)v1[j]; }
    *(bf16x8*)(dst + i*8) = o;
  }
}

// --------- xg_x precompute: xgx[lt][c][b64][n96] = x@W_x[:256]+b (bf16) ----
__global__ void __launch_bounds__(256) xgx_kernel(const bf16* __restrict__ xT,
                                                  const bf16* __restrict__ Wxx,
                                                  const float* __restrict__ bias,
                                                  bf16* __restrict__ xgx,
                                                  unsigned t0)
{
  __shared__ bf16 WxS[24576];
  __shared__ bf16 otile[6144];
  unsigned bid = blockIdx.x, lt = bid>>4, c = bid&15u, tid = threadIdx.x;
  unsigned t = t0 + lt;
  { const u32x4* s = (const u32x4*)(Wxx + (size_t)c*24576u); u32x4* d = (u32x4*)WxS;
    #pragma unroll
    for (int i=0;i<12;i++) d[tid+256u*i] = s[tid+256u*i]; }
  __syncthreads();
  unsigned wave = tid>>6, lane = tid&63u, q = lane>>4, m = lane&15u;
  f32x4 zero4 = {0.f,0.f,0.f,0.f};
  f32x4 acc[6];
  #pragma unroll
  for (int nt=0;nt<6;nt++) acc[nt] = zero4;
  const bf16* ap = xT + (size_t)t*16384u + (16u*wave + m)*256u + q*8u;
  #pragma unroll
  for (int kc=0;kc<8;kc++) {
    bf16x8 a = *(const bf16x8*)(ap + kc*32);
    #pragma unroll
    for (int nt=0;nt<6;nt++) {
      bf16x8 bb = *(const bf16x8*)(WxS + (((unsigned)kc*4u+q)*96u + (unsigned)nt*16u + m)*8u);
      acc[nt] = mfma16(a, bb, acc[nt]);
    }
  }
  #pragma unroll
  for (int nt=0;nt<6;nt++) {
    unsigned n = (unsigned)nt*16u + m;
    unsigned colg = (n>>5)*512u + c*32u + (n&31u);
    float bv = bias[colg];
    #pragma unroll
    for (int reg=0;reg<4;reg++)
      otile[(16u*wave + 4u*q + (unsigned)reg)*96u + n] = (bf16)(acc[nt][reg] + bv);
  }
  __syncthreads();
  { u32x4* d = (u32x4*)(xgx + (size_t)(lt*16u + c)*6144u);
    const u32x4* s = (const u32x4*)otile;
    #pragma unroll
    for (int i=0;i<3;i++) d[tid+256u*i] = s[tid+256u*i]; }
}

// ------------------------------ grid barrier -------------------------------
__device__ __forceinline__ void grid_barrier(unsigned* __restrict__ bar,
                                             unsigned tid, unsigned k)
{
  __syncthreads();   // drains vmcnt -> all wg stores (agent scope) at LLC
  if (tid == 0) {
    unsigned old = __hip_atomic_fetch_add(&bar[0], 1u, __ATOMIC_RELAXED,
                                          __HIP_MEMORY_SCOPE_AGENT);
    if (old == NWG*(k+1u) - 1u) {
      __hip_atomic_store(&bar[32], k+1u, __ATOMIC_RELAXED,
                         __HIP_MEMORY_SCOPE_AGENT);
    } else {
      unsigned g;
      do { __builtin_amdgcn_s_sleep(2);
           g = __hip_atomic_load(&bar[32], __ATOMIC_RELAXED,
                                 __HIP_MEMORY_SCOPE_AGENT);
      } while (g < k+1u);
    }
    __builtin_amdgcn_fence(__ATOMIC_ACQUIRE, "agent"); // invalidate stale L1/L2
  }
  __syncthreads();
}

// ------------------------------ recurrent kernel ---------------------------
// grid = 128: r = blockIdx>>4 (row-block of 32 rows), c = blockIdx&15 (h-cols
// [32c,32c+32)). LDS overlay region R (12288 B): phases 1-2 use stg(2KB)+
// zgSf(4KB, fp32); phase 3 uses muS(4KB bf16)+rawS(8KB fp32). Disjoint in time.
#define LDS_REC 159744
__global__ void __launch_bounds__(256, 1) rec_kernel(
    const bf16* __restrict__ Whs_g, const bf16* __restrict__ Wxz_g,
    const bf16* __restrict__ Wdf_g, const bf16* __restrict__ xgx,
    const float* __restrict__ noise, const float* __restrict__ b_d,
    float* __restrict__ out, bf16* __restrict__ hbuf, bf16* __restrict__ ubuf,
    bf16* __restrict__ zbuf, unsigned* __restrict__ bar,
    unsigned t0, unsigned tlen)
{
  extern __shared__ char smem[];
  bf16*  WhS  = (bf16*)(smem);            // 49152 el = 98304 B
  bf16*  WxzS = (bf16*)(smem + 98304);    // 6144 el = 12288 B
  bf16*  hA   = (bf16*)(smem + 110592);   // 16384 el  [kc16][q4][row32][j8]
  bf16*  zA   = (bf16*)(smem + 143360);   // 2048 el   [kc2][q4][row32][j8]
  bf16*  stg  = (bf16*)(smem + 147456);   // 1024 el   [q4][row32][j8]
  float* zgSf = (float*)(smem + 149504);  // 1024 el   [row32][col32] fp32
  bf16*  muS  = (bf16*)(smem + 147456);   // 2048 el   [row32][col64] (overlay)
  float* rawS = (float*)(smem + 151552);  // 2048 el   [row32][col64] fp32

  const unsigned tid = threadIdx.x;
  const unsigned wave = tid>>6, lane = tid&63u, q = lane>>4, m = lane&15u;
  const unsigned mt = wave&1u, gt = wave>>1;   // ph1: gate gt; ph2: N-tile gt
  const unsigned r = blockIdx.x>>4, c = blockIdx.x&15u;
  const unsigned b0 = (r&1u)*32u;
  const unsigned rowG0 = r*32u;
  const unsigned zrow = tid>>3, zi = tid&7u;

  // ---- stage resident weights ----
  { const u32x4* s = (const u32x4*)(Whs_g + (size_t)c*49152u); u32x4* d = (u32x4*)WhS;
    #pragma unroll
    for (int i=0;i<24;i++) d[tid+256u*i] = s[tid+256u*i]; }
  { const u32x4* s = (const u32x4*)(Wxz_g + (size_t)c*6144u); u32x4* d = (u32x4*)WxzS;
    #pragma unroll
    for (int i=0;i<3;i++) d[tid+256u*i] = s[tid+256u*i]; }
  // ---- W_d fragments in VGPRs (cols [32*wave, 32*wave+32)) ----
  bf16x8 wd[16][2];
  #pragma unroll
  for (int kc=0;kc<16;kc++) {
    #pragma unroll
    for (int nw=0;nw<2;nw++)
      wd[kc][nw] = *(const bf16x8*)(Wdf_g +
          ((((unsigned)kc*4u+q)*128u + wave*32u + (unsigned)nw*16u + m)*8u));
  }
  float bd0 = b_d[wave*32u + m], bd1 = b_d[wave*32u + 16u + m];
  // ---- init state ----
  float hstate[4];   // fp32 carry of own h tile: rows 16mt+4q+reg, col gt*16+m
  if (t0 == 0) {
    u32x4 zz = {0,0,0,0};
    u32x4* d = (u32x4*)hA;
    #pragma unroll
    for (int i=0;i<8;i++) d[tid+256u*i] = zz;
    ((u32x4*)zA)[tid] = zz;
    #pragma unroll
    for (int reg=0;reg<4;reg++) hstate[reg] = 0.f;
    __syncthreads();
  } else {
    const u32x4* s = (const u32x4*)(hbuf + ((size_t)(1u*8u + r)*16u)*1024u); // parity 1
    u32x4* d = (u32x4*)hA;
    #pragma unroll
    for (int i=0;i<8;i++) d[tid+256u*i] = s[tid+256u*i];
    bf16x8 zv = *(const bf16x8*)(zbuf + ((size_t)(rowG0 + zrow)*64u + zi*8u));
    *(bf16x8*)(zA + ((size_t)zi*32u + zrow)*8u) = zv;
    __syncthreads();
    unsigned cl = gt*16u + m;
    #pragma unroll
    for (int reg=0;reg<4;reg++)
      hstate[reg] = (float)hA[((c*4u + (cl>>3))*32u + 16u*mt + 4u*q + (unsigned)reg)*8u + (cl&7u)];
  }

  const unsigned tend = t0 + tlen;
  for (unsigned t = t0; t < tend; ++t) {
    unsigned par = t & 1u;
    unsigned kb = 2u*(t - t0);
    // ---- early global loads (latency hidden under GEMMs) ----
    __bf16 xv1[2][4]; __bf16 xv2[4];
    { size_t base = ((size_t)((t - t0)*16u + c)*64u + b0 + 16u*mt + 4u*q)*96u + m;
      #pragma unroll
      for (int nt=0;nt<2;nt++)
        #pragma unroll
        for (int reg=0;reg<4;reg++)
          xv1[nt][reg] = xgx[base + (unsigned)reg*96u + gt*32u + (unsigned)nt*16u];
      #pragma unroll
      for (int reg=0;reg<4;reg++)
        xv2[reg] = xgx[base + (unsigned)reg*96u + 64u + gt*16u];
    }
    f32x4 eps0, eps1;
    { const float* np = noise + ((size_t)t*256u + rowG0 + zrow)*64u + zi*8u;
      eps0 = *(const f32x4*)np; eps1 = *(const f32x4*)(np + 4); }

    // ================= phase 1: z/r gates, u = r*h =================
    f32x4 accP0 = {0.f,0.f,0.f,0.f}, accP1 = {0.f,0.f,0.f,0.f};
    #pragma unroll
    for (int kc=0;kc<2;kc++) {
      bf16x8 a = *(const bf16x8*)(zA + (((unsigned)kc*4u+q)*32u + 16u*mt + m)*8u);
      accP0 = mfma16(a, *(const bf16x8*)(WxzS + (((unsigned)kc*4u+q)*96u + gt*32u + m)*8u), accP0);
      accP1 = mfma16(a, *(const bf16x8*)(WxzS + (((unsigned)kc*4u+q)*96u + gt*32u + 16u + m)*8u), accP1);
    }
    #pragma unroll
    for (int kc=0;kc<16;kc++) {
      bf16x8 a = *(const bf16x8*)(hA + (((unsigned)kc*4u+q)*32u + 16u*mt + m)*8u);
      accP0 = mfma16(a, *(const bf16x8*)(WhS + (((unsigned)kc*4u+q)*96u + gt*32u + m)*8u), accP0);
      accP1 = mfma16(a, *(const bf16x8*)(WhS + (((unsigned)kc*4u+q)*96u + gt*32u + 16u + m)*8u), accP1);
    }
    #pragma unroll
    for (int reg=0;reg<4;reg++) {
      unsigned rloc = 16u*mt + 4u*q + (unsigned)reg;
      float g0 = accP0[reg] + (float)xv1[0][reg];
      float g1 = accP1[reg] + (float)xv1[1][reg];
      float s0 = 1.f/(1.f + __expf(-g0));
      float s1 = 1.f/(1.f + __expf(-g1));
      if (gt == 0) {          // z-gate -> zgSf (fp32)
        zgSf[rloc*32u + m]       = s0;
        zgSf[rloc*32u + 16u + m] = s1;
      } else {                // r-gate -> u = r*h staged frag-major
        unsigned cl0 = m, cl1 = 16u + m;
        float h0 = (float)hA[((c*4u + (cl0>>3))*32u + rloc)*8u + (cl0&7u)];
        float h1 = (float)hA[((c*4u + (cl1>>3))*32u + rloc)*8u + (cl1&7u)];
        stg[((cl0>>3)*32u + rloc)*8u + (cl0&7u)] = (bf16)(s0*h0);
        stg[((cl1>>3)*32u + rloc)*8u + (cl1&7u)] = (bf16)(s1*h1);
      }
    }
    __syncthreads();
    // u slice -> ubuf (device-scope stores: visible at LLC)
    { size_t blk = ((size_t)(par*8u + r)*16u + c)*1024u;
      unsigned long long v = *(const unsigned long long*)(stg + (size_t)tid*4u);
      __hip_atomic_store((unsigned long long*)(ubuf + blk + (size_t)tid*4u), v,
                         __ATOMIC_RELAXED, __HIP_MEMORY_SCOPE_AGENT); }
    grid_barrier(bar, tid, kb);
    // load full u for own rows
    { const u32x4* s = (const u32x4*)(ubuf + ((size_t)(par*8u + r)*16u)*1024u);
      u32x4* d = (u32x4*)hA;
      #pragma unroll
      for (int i=0;i<8;i++) d[tid+256u*i] = s[tid+256u*i]; }
    __syncthreads();

    // ================= phase 2: n_cand, h_new =================
    // n preact = xg_n(x part, xv2) + z_prev@W_x[D:,2H:] + (r*h)@W_h[:,2H:]
    f32x4 accN = {0.f,0.f,0.f,0.f};
    #pragma unroll
    for (int kc=0;kc<2;kc++) {   // R2 FIX: z_prev contribution to n-gate
      bf16x8 a = *(const bf16x8*)(zA + (((unsigned)kc*4u+q)*32u + 16u*mt + m)*8u);
      accN = mfma16(a, *(const bf16x8*)(WxzS + (((unsigned)kc*4u+q)*96u + 64u + gt*16u + m)*8u), accN);
    }
    #pragma unroll
    for (int kc=0;kc<16;kc++) {
      bf16x8 a = *(const bf16x8*)(hA + (((unsigned)kc*4u+q)*32u + 16u*mt + m)*8u);
      accN = mfma16(a, *(const bf16x8*)(WhS + (((unsigned)kc*4u+q)*96u + 64u + gt*16u + m)*8u), accN);
    }
    { unsigned colL2 = gt*16u + m;
      #pragma unroll
      for (int reg=0;reg<4;reg++) {
        unsigned rloc = 16u*mt + 4u*q + (unsigned)reg;
        float zg = zgSf[rloc*32u + colL2];
        float pre = accN[reg] + (float)xv2[reg];
        float e2 = __expf(2.f*pre);
        float nc = 1.f - 2.f/(e2 + 1.f);
        float hn = (1.f - zg)*nc + zg*hstate[reg];   // fp32 state carry
        hstate[reg] = hn;
        stg[((colL2>>3)*32u + rloc)*8u + (colL2&7u)] = (bf16)hn;
      }
    }
    __syncthreads();
    { size_t blk = ((size_t)(par*8u + r)*16u + c)*1024u;
      unsigned long long v = *(const unsigned long long*)(stg + (size_t)tid*4u);
      __hip_atomic_store((unsigned long long*)(hbuf + blk + (size_t)tid*4u), v,
                         __ATOMIC_RELAXED, __HIP_MEMORY_SCOPE_AGENT); }
    grid_barrier(bar, tid, kb + 1u);
    // load full h_new for own rows
    { const u32x4* s = (const u32x4*)(hbuf + ((size_t)(par*8u + r)*16u)*1024u);
      u32x4* d = (u32x4*)hA;
      #pragma unroll
      for (int i=0;i<8;i++) d[tid+256u*i] = s[tid+256u*i]; }
    __syncthreads();

    // ================= phase 3: dp = h_new@W_d, sample, outputs =========
    f32x4 dp00={0.f,0.f,0.f,0.f}, dp01={0.f,0.f,0.f,0.f};
    f32x4 dp10={0.f,0.f,0.f,0.f}, dp11={0.f,0.f,0.f,0.f};
    #pragma unroll
    for (int kc=0;kc<16;kc++) {
      bf16x8 a0 = *(const bf16x8*)(hA + (((unsigned)kc*4u+q)*32u + m)*8u);
      bf16x8 a1 = *(const bf16x8*)(hA + (((unsigned)kc*4u+q)*32u + 16u + m)*8u);
      dp00 = mfma16(a0, wd[kc][0], dp00);
      dp01 = mfma16(a0, wd[kc][1], dp01);
      dp10 = mfma16(a1, wd[kc][0], dp10);
      dp11 = mfma16(a1, wd[kc][1], dp11);
    }
    if (wave < 2u) {   // mu cols 0..63 -> muS (bf16)
      #pragma unroll
      for (int reg=0;reg<4;reg++) {
        unsigned r0 = 4u*q + (unsigned)reg;
        muS[r0*64u + wave*32u + m]              = (bf16)(dp00[reg] + bd0);
        muS[r0*64u + wave*32u + 16u + m]        = (bf16)(dp01[reg] + bd1);
        muS[(r0+16u)*64u + wave*32u + m]        = (bf16)(dp10[reg] + bd0);
        muS[(r0+16u)*64u + wave*32u + 16u + m]  = (bf16)(dp11[reg] + bd1);
      }
    } else {           // raw cols 64..127 -> rawS (fp32)
      unsigned cb = (wave - 2u)*32u;
      #pragma unroll
      for (int reg=0;reg<4;reg++) {
        unsigned r0 = 4u*q + (unsigned)reg;
        rawS[r0*64u + cb + m]              = dp00[reg] + bd0;
        rawS[r0*64u + cb + 16u + m]        = dp01[reg] + bd1;
        rawS[(r0+16u)*64u + cb + m]        = dp10[reg] + bd0;
        rawS[(r0+16u)*64u + cb + 16u + m]  = dp11[reg] + bd1;
      }
    }
    __syncthreads();
    {
      bf16x8 mu8 = *(const bf16x8*)(muS + (size_t)zrow*64u + zi*8u);
      f32x4 rw0 = *(const f32x4*)(rawS + (size_t)zrow*64u + zi*8u);
      f32x4 rw1 = *(const f32x4*)(rawS + (size_t)zrow*64u + zi*8u + 4u);
      float ent = 0.f, lp = 0.f;
      float zf[8];
      #pragma unroll
      for (int j=0;j<8;j++) {
        float raw = (j < 4) ? rw0[j] : rw1[j-4];
        float sp = (raw > 20.f) ? raw : __logf(1.f + __expf(raw));
        sp += 1e-4f;
        float ls = __logf(sp);
        float e = (j < 4) ? eps0[j] : eps1[j-4];
        float zv = (float)mu8[j] + sp*e;
        zf[j] = zv;
        ent += ls;
        lp  -= 0.5f*e*e + ls;
      }
      ent += 8.f*1.4189385332046727f;
      lp  -= 8.f*0.9189385332046727f;
      bf16x8 zb;
      #pragma unroll
      for (int j=0;j<8;j++) zb[j] = (bf16)zf[j];
      *(bf16x8*)(zA + ((size_t)zi*32u + zrow)*8u) = zb;
      if (c == 0) {
        float* zo = out + ((size_t)(rowG0 + zrow)*1024u + t)*64u + zi*8u;
        f32x4 o0 = {zf[0],zf[1],zf[2],zf[3]}, o1 = {zf[4],zf[5],zf[6],zf[7]};
        *(f32x4*)zo = o0; *((f32x4*)zo + 1) = o1;
        if (t == tend - 1u)  // carry z across chunk boundary
          *(bf16x8*)(zbuf + ((size_t)(rowG0 + zrow)*64u + zi*8u)) = zb;
      }
      ent += __shfl_down(ent, 4); lp += __shfl_down(lp, 4);
      ent += __shfl_down(ent, 2); lp += __shfl_down(lp, 2);
      ent += __shfl_down(ent, 1); lp += __shfl_down(lp, 1);
      if (zi == 0u && c == 0u) {
        out[16777216u + (size_t)(rowG0 + zrow)*1024u + t] = ent;
        out[17039360u + (size_t)(rowG0 + zrow)*1024u + t] = lp;
      }
    }
    __syncthreads();
  }
}

// ------------------------------- host --------------------------------------
extern "C" void kernel_launch(void* const* d_in, const int* in_sizes, int n_in,
                              void* d_out, int out_size, void* d_ws, size_t ws_size,
                              hipStream_t stream)
{
  const float* x     = (const float*)d_in[0];
  const float* noise = (const float*)d_in[1];
  const float* W_x   = (const float*)d_in[2];
  const float* W_h   = (const float*)d_in[3];
  const float* bias  = (const float*)d_in[4];
  const float* W_d   = (const float*)d_in[5];
  const float* b_d   = (const float*)d_in[6];
  float* out = (float*)d_out;
  char* ws = (char*)d_ws;

  size_t off = 0;
  unsigned* bar = (unsigned*)(ws + off);  off += 16*256;          // 16 barrier regions
  bf16* Wdf  = (bf16*)(ws + off);         off += 65536ull*2;
  bf16* Whs  = (bf16*)(ws + off);         off += 786432ull*2;
  bf16* Wxz  = (bf16*)(ws + off);         off += 98304ull*2;
  bf16* Wxx  = (bf16*)(ws + off);         off += 393216ull*2;
  bf16* hbuf = (bf16*)(ws + off);         off += 262144ull*2;
  bf16* ubuf = (bf16*)(ws + off);         off += 262144ull*2;
  bf16* zbuf = (bf16*)(ws + off);         off += 16384ull*2;
  bf16* xT   = (bf16*)(ws + off);         off += 16777216ull*2;
  bf16* xgx  = (bf16*)(ws + off);         // tlen*16*64*96 bf16 (chunked)
  size_t fixed = off;

  unsigned tlen = 1024;
  while (tlen > 64 && fixed + (size_t)tlen*196608ull > ws_size) tlen >>= 1;
  unsigned nch = 1024/tlen;

  hipMemsetAsync(bar, 0, 16*256, stream);
  repack_kernel<<<5248, 256, 0, stream>>>(W_x, W_h, W_d, Whs, Wxz, Wdf, Wxx);
  xpose_kernel<<<1024, 256, 0, stream>>>(x, xT);
  hipFuncSetAttribute((const void*)rec_kernel,
                      hipFuncAttributeMaxDynamicSharedMemorySize, LDS_REC);
  for (unsigned ch = 0; ch < nch; ++ch) {
    unsigned t0 = ch*tlen;
    xgx_kernel<<<tlen*16, 256, 0, stream>>>(xT, Wxx, bias, xgx, t0);
    rec_kernel<<<NWG, 256, LDS_REC, stream>>>(Whs, Wxz, Wdf, xgx, noise, b_d,
                                              out, hbuf, ubuf, zbuf,
                                              bar + (size_t)ch*64u, t0, tlen);
  }
}